// Round 3
// baseline (890.969 us; speedup 1.0000x reference)
//
#include <hip/hip_runtime.h>
#include <stdint.h>

#define T_STEPS 500
#define NBATCH  128
#define NIN     784
#define KPAD    800
#define NH      1024
#define NSL     102
#define DECAY   0.8807970779778823f

typedef __attribute__((ext_vector_type(8))) short short8;
typedef __attribute__((ext_vector_type(4))) float f32x4;
typedef unsigned int u32;

static __device__ __forceinline__ unsigned short f2bf(float f) {
  union { float f; u32 u; } v; v.f = f;
  u32 r = (v.u + 0x7FFFu + ((v.u >> 16) & 1u)) >> 16;
  return (unsigned short)r;
}
static __device__ __forceinline__ float uf(u32 u) {
  union { u32 u; float f; } v; v.u = u; return v.f;
}
static __device__ __forceinline__ u32 fu(float f) {
  union { float f; u32 u; } v; v.f = f; return v.u;
}
static __device__ __forceinline__ void gl16(const void* g, void* l) {
  __builtin_amdgcn_global_load_lds((const __attribute__((address_space(1))) u32*)g,
                                   (__attribute__((address_space(3))) u32*)l, 16, 0, 0);
}

// ---- prep: tiled transpose fc1[784][1024] -> fc1T[1024][800] bf16 (K pad 0) ----
__global__ __launch_bounds__(256) void prep_kernel(
    const float* __restrict__ fc1, unsigned short* __restrict__ fc1T,
    float* __restrict__ out_last) {
  __shared__ float tile[32][33];
  const int kb = blockIdx.x * 32, nb = blockIdx.y * 32;
  const int tx = threadIdx.x, ty = threadIdx.y;
#pragma unroll
  for (int i = 0; i < 4; ++i) {
    int k = kb + ty + i * 8, n = nb + tx;
    tile[ty + i * 8][tx] = (k < NIN) ? fc1[(size_t)k * NH + n] : 0.0f;
  }
  __syncthreads();
#pragma unroll
  for (int i = 0; i < 4; ++i) {
    int n = nb + ty + i * 8, k = kb + tx;
    fc1T[(size_t)n * KPAD + k] = f2bf(tile[tx][ty + i * 8]);
  }
  if (kb == 0 && nb == 0 && tx == 0 && ty == 0) *out_last = 500.0f;
}

// ---- colsum[h] = sum_j wrec[j][h]  (for the all-fire burst fast path) -------
__global__ __launch_bounds__(256) void colsum_kernel(
    const float* __restrict__ wrec, float* __restrict__ colsum) {
  const int h = blockIdx.x * 256 + threadIdx.x;
  float s0 = 0.f, s1 = 0.f, s2 = 0.f, s3 = 0.f;
  for (int j = 0; j < NH; j += 4) {
    s0 += wrec[(size_t)j * NH + h];
    s1 += wrec[(size_t)(j + 1) * NH + h];
    s2 += wrec[(size_t)(j + 2) * NH + h];
    s3 += wrec[(size_t)(j + 3) * NH + h];
  }
  colsum[h] = (s0 + s1) + (s2 + s3);
}

// ---- GEMM: curq[64000][1024](bf16) = X[64000][784](fp32) @ fc1 (unchanged) --
__global__ __launch_bounds__(256) void gemm_kernel(
    const float* __restrict__ x, const unsigned short* __restrict__ fc1T,
    unsigned short* __restrict__ curq) {
  __shared__ __align__(16) float Af[128 * 32];
  __shared__ __align__(16) unsigned short Bs[128 * 32];

  const int tid = threadIdx.x;
  const int n0 = blockIdx.x * 128, m0 = blockIdx.y * 128;
  const int lane = tid & 63, wave = tid >> 6;
  const int wr = (wave >> 1) * 64, wc = (wave & 1) * 64;
  const int l16 = lane & 15, q = lane >> 4;

  const int a_irow = lane >> 3;
  const int a_g = (lane & 7) ^ (a_irow & 7);
  const int a_col = a_g * 4;
  const int b_irow = lane >> 2;
  const int b_col = (lane & 3) * 8;

  f32x4 acc[4][4];
  const f32x4 z4 = {0.f, 0.f, 0.f, 0.f};
#pragma unroll
  for (int i = 0; i < 4; ++i)
#pragma unroll
    for (int j = 0; j < 4; ++j) acc[i][j] = z4;

  for (int k0 = 0; k0 < KPAD; k0 += 32) {
#pragma unroll
    for (int l = 0; l < 4; ++l) {
      const int rbase = wave * 32 + l * 8;
      if (k0 + a_col < NIN)
        gl16(x + (size_t)(m0 + rbase + a_irow) * NIN + k0 + a_col,
             &Af[rbase * 32]);
    }
#pragma unroll
    for (int l = 0; l < 2; ++l) {
      const int rbase = wave * 32 + l * 16;
      gl16(fc1T + (size_t)(n0 + rbase + b_irow) * KPAD + k0 + b_col,
           &Bs[rbase * 32]);
    }
    __syncthreads();

    short8 av[4], bv[4];
#pragma unroll
    for (int i = 0; i < 4; ++i) {
      const int r = wr + i * 16 + l16;
      const int s0 = (2 * q) ^ (l16 & 7);
      const float4 alo = *(const float4*)&Af[r * 32 + s0 * 4];
      const float4 ahi = *(const float4*)&Af[r * 32 + (s0 ^ 1) * 4];
      union { short8 s; u32 u[4]; } p;
      p.u[0] = __builtin_amdgcn_perm(fu(alo.y), fu(alo.x), 0x07060302u);
      p.u[1] = __builtin_amdgcn_perm(fu(alo.w), fu(alo.z), 0x07060302u);
      p.u[2] = __builtin_amdgcn_perm(fu(ahi.y), fu(ahi.x), 0x07060302u);
      p.u[3] = __builtin_amdgcn_perm(fu(ahi.w), fu(ahi.z), 0x07060302u);
      av[i] = p.s;
      bv[i] = *(const short8*)&Bs[(wc + i * 16 + l16) * 32 + q * 8];
    }
#pragma unroll
    for (int i = 0; i < 4; ++i)
#pragma unroll
      for (int j = 0; j < 4; ++j)
        acc[i][j] = __builtin_amdgcn_mfma_f32_16x16x32_bf16(av[i], bv[j],
                                                            acc[i][j], 0, 0, 0);
    __syncthreads();
  }

#pragma unroll
  for (int i = 0; i < 4; ++i)
#pragma unroll
    for (int j = 0; j < 4; ++j) {
      const int row = m0 + wr + i * 16 + q * 4;
      const int col = n0 + wc + j * 16 + l16;
#pragma unroll
      for (int rr = 0; rr < 4; ++rr)
        curq[(size_t)(row + rr) * NH + col] = f2bf(acc[i][j][rr]);
    }
}

// ---- scan: ONE WAVE per batch, zero barriers, zero LDS ----------------------
// lane handles h = lane*16 .. lane*16+15. Spike-delta set communicated via
// ballot + shfl (wave-uniform branches). Burst (>=48 lanes changed) resets
// rs from precomputed colsum minus currently-silent rows (exact).
__global__ __launch_bounds__(64) void scan_kernel(
    const unsigned short* __restrict__ curq, const float* __restrict__ wrec,
    const float* __restrict__ colsum, float* __restrict__ out) {
  const int b = blockIdx.x;
  const int lane = threadIdx.x;
  const int h0 = lane * 16;
  const size_t rowbase = (size_t)b * T_STEPS;

  float mem[16], rs[16], sp[16];
#pragma unroll
  for (int c = 0; c < 16; ++c) { mem[c] = 0.f; rs[c] = 0.f; sp[c] = 0.f; }
  u32 spbits = 0, chgpack = 0;
  unsigned long long pend = 0;

  uint4 cv[2][4][2];  // [buf][step-in-chunk][half], 16 bf16 per step per lane
#pragma unroll
  for (int u = 0; u < 4; ++u) {
    const uint4* p = (const uint4*)&curq[(rowbase + u) * NH + h0];
    cv[0][u][0] = p[0]; cv[0][u][1] = p[1];
  }

  for (int tb = 0; tb < T_STEPS; tb += 4) {
    const int cb = (tb >> 2) & 1;
    if (tb + 4 < T_STEPS) {
#pragma unroll
      for (int u = 0; u < 4; ++u) {
        const uint4* p = (const uint4*)&curq[(rowbase + tb + 4 + u) * NH + h0];
        cv[cb ^ 1][u][0] = p[0]; cv[cb ^ 1][u][1] = p[1];
      }
    }
#pragma unroll
    for (int u = 0; u < 4; ++u) {
      const int t = tb + u;

      // ---- apply pending spike-set deltas from step t-1 (wave-uniform) ----
      if (__builtin_expect(pend != 0ull, 0)) {
        if (__popcll(pend) >= 48) {
          // burst: full reset from column sums, subtract silent rows
#pragma unroll
          for (int c = 0; c < 16; c += 4) {
            const float4 cs = *(const float4*)&colsum[h0 + c];
            rs[c] = cs.x; rs[c + 1] = cs.y; rs[c + 2] = cs.z; rs[c + 3] = cs.w;
          }
          const u32 myz = (~spbits) & 0xFFFFu;
          unsigned long long zm = __ballot(myz != 0);
          while (zm) {
            const int l = __builtin_ctzll(zm); zm &= zm - 1;
            u32 zb = __shfl(myz, l, 64);
            while (zb) {
              const int c = __builtin_ctz(zb); zb &= zb - 1;
              const float* w = &wrec[(size_t)(l * 16 + c) * NH + h0];
#pragma unroll
              for (int qq = 0; qq < 4; ++qq) {
                const float4 wv = *(const float4*)(w + 4 * qq);
                rs[4 * qq] -= wv.x; rs[4 * qq + 1] -= wv.y;
                rs[4 * qq + 2] -= wv.z; rs[4 * qq + 3] -= wv.w;
              }
            }
          }
        } else {
          unsigned long long dm = pend;
          while (dm) {
            const int l = __builtin_ctzll(dm); dm &= dm - 1;
            const u32 pk = __shfl(chgpack, l, 64);
            u32 cbits = pk >> 16;
            while (cbits) {
              const int c = __builtin_ctz(cbits); cbits &= cbits - 1;
              const float s = ((pk >> c) & 1u) ? 1.0f : -1.0f;
              const float* w = &wrec[(size_t)(l * 16 + c) * NH + h0];
#pragma unroll
              for (int qq = 0; qq < 4; ++qq) {
                const float4 wv = *(const float4*)(w + 4 * qq);
                rs[4 * qq]     = fmaf(s, wv.x, rs[4 * qq]);
                rs[4 * qq + 1] = fmaf(s, wv.y, rs[4 * qq + 1]);
                rs[4 * qq + 2] = fmaf(s, wv.z, rs[4 * qq + 2]);
                rs[4 * qq + 3] = fmaf(s, wv.w, rs[4 * qq + 3]);
              }
            }
          }
        }
        pend = 0;
      }

      // ---- extract cur_in (bf16 -> f32, 2 ops per pair) ----
      const uint4 A = cv[cb][u][0], B = cv[cb][u][1];
      const u32 dw[8] = {A.x, A.y, A.z, A.w, B.x, B.y, B.z, B.w};
      float cin[16];
#pragma unroll
      for (int k = 0; k < 8; ++k) {
        cin[2 * k]     = uf(dw[k] << 16);
        cin[2 * k + 1] = uf(dw[k] & 0xFFFF0000u);
      }

      // ---- leaky integrate + fire ----
      u32 newbits = 0;
      float ns[16];
#pragma unroll
      for (int c = 0; c < 16; ++c) {
        const float f = fmaf(-DECAY, sp[c], DECAY);   // DECAY*(1-sp)
        mem[c] = fmaf(mem[c], f, cin[c] + rs[c]);
        const bool fire = mem[c] >= 1.0f;
        ns[c] = fire ? 1.0f : 0.0f;
        newbits |= fire ? (1u << c) : 0u;
      }

      // ---- output slice spk[:, :102] (lanes 0..6 only; 8B-aligned stores) --
      if (lane < 7) {
        float2* o = (float2*)(out + (rowbase + t) * NSL + h0);
        const int n2 = (lane == 6) ? 3 : 8;
#pragma unroll
        for (int k = 0; k < 8; ++k)
          if (k < n2) o[k] = make_float2(ns[2 * k], ns[2 * k + 1]);
      }

      // ---- record deltas for step t+1 ----
      const u32 chg = spbits ^ newbits;
      pend = __ballot(chg != 0);
      chgpack = (chg << 16) | newbits;
      spbits = newbits;
#pragma unroll
      for (int c = 0; c < 16; ++c) sp[c] = ns[c];
    }
  }
}

extern "C" void kernel_launch(void* const* d_in, const int* in_sizes, int n_in,
                              void* d_out, int out_size, void* d_ws, size_t ws_size,
                              hipStream_t stream) {
  const float* x    = (const float*)d_in[0];  // [128][500][784] fp32
  const float* fc1  = (const float*)d_in[1];  // [784][1024] fp32
  const float* wrec = (const float*)d_in[2];  // [1024][1024] fp32
  float* out = (float*)d_out;                 // [128*500*102] + [1]

  unsigned short* fc1T = (unsigned short*)d_ws;                     // 1,638,400 B
  float* colsum = (float*)((char*)d_ws + 1638400);                  // 4,096 B
  unsigned short* curq = (unsigned short*)((char*)d_ws + 1642496);  // 131,072,000 B

  prep_kernel<<<dim3(25, 32), dim3(32, 8), 0, stream>>>(fc1, fc1T,
                                                        out + (out_size - 1));
  colsum_kernel<<<dim3(4), 256, 0, stream>>>(wrec, colsum);
  gemm_kernel<<<dim3(8, 500), 256, 0, stream>>>(x, fc1T, curq);
  scan_kernel<<<dim3(NBATCH), 64, 0, stream>>>(curq, wrec, colsum, out);
}

// Round 4
// 669.814 us; speedup vs baseline: 1.3302x; 1.3302x over previous
//
#include <hip/hip_runtime.h>
#include <stdint.h>

#define T_STEPS 500
#define NBATCH  128
#define NIN     784
#define KPAD    800
#define NH      1024
#define NSL     102
#define DECAY   0.8807970779778823f

typedef __attribute__((ext_vector_type(8))) short short8;
typedef __attribute__((ext_vector_type(4))) float f32x4;
typedef unsigned int u32;
typedef unsigned long long u64;

static __device__ __forceinline__ unsigned short f2bf(float f) {
  union { float f; u32 u; } v; v.f = f;
  u32 r = (v.u + 0x7FFFu + ((v.u >> 16) & 1u)) >> 16;
  return (unsigned short)r;
}
static __device__ __forceinline__ float uf(u32 u) {
  union { u32 u; float f; } v; v.u = u; return v.f;
}
static __device__ __forceinline__ u32 fu(float f) {
  union { float f; u32 u; } v; v.f = f; return v.u;
}
static __device__ __forceinline__ void gl16(const void* g, void* l) {
  __builtin_amdgcn_global_load_lds((const __attribute__((address_space(1))) u32*)g,
                                   (__attribute__((address_space(3))) u32*)l, 16, 0, 0);
}

// ---- prep: transpose fc1 -> fc1T[1024][800] bf16 (K pad 0); zero colsum ----
__global__ __launch_bounds__(256) void prep_kernel(
    const float* __restrict__ fc1, unsigned short* __restrict__ fc1T,
    float* __restrict__ colsum, float* __restrict__ out_last) {
  __shared__ float tile[32][33];
  const int kb = blockIdx.x * 32, nb = blockIdx.y * 32;
  const int tx = threadIdx.x, ty = threadIdx.y;
#pragma unroll
  for (int i = 0; i < 4; ++i) {
    int k = kb + ty + i * 8, n = nb + tx;
    tile[ty + i * 8][tx] = (k < NIN) ? fc1[(size_t)k * NH + n] : 0.0f;
  }
  __syncthreads();
#pragma unroll
  for (int i = 0; i < 4; ++i) {
    int n = nb + ty + i * 8, k = kb + tx;
    fc1T[(size_t)n * KPAD + k] = f2bf(tile[tx][ty + i * 8]);
  }
  if (kb == 0 && nb == 0) {
    const int t = ty * 32 + tx;  // 0..255 -> zero 1024 floats
    const float4 z = {0.f, 0.f, 0.f, 0.f};
    ((float4*)colsum)[t] = z;
    if (t == 0) *out_last = 500.0f;
  }
}

// ---- colsum[h] = sum_j wrec[j][h]; grid (4 col-groups, 32 row-slices) ------
__global__ __launch_bounds__(256) void colsum_kernel(
    const float* __restrict__ wrec, float* __restrict__ colsum) {
  const int h = blockIdx.x * 256 + threadIdx.x;
  const int j0 = blockIdx.y * 32;
  float s0 = 0.f, s1 = 0.f, s2 = 0.f, s3 = 0.f;
#pragma unroll
  for (int j = 0; j < 32; j += 4) {
    s0 += wrec[(size_t)(j0 + j) * NH + h];
    s1 += wrec[(size_t)(j0 + j + 1) * NH + h];
    s2 += wrec[(size_t)(j0 + j + 2) * NH + h];
    s3 += wrec[(size_t)(j0 + j + 3) * NH + h];
  }
  atomicAdd(&colsum[h], (s0 + s1) + (s2 + s3));
}

// ---- GEMM: curq[64000][1024](bf16) = X[64000][784](fp32) @ fc1 (unchanged) --
__global__ __launch_bounds__(256) void gemm_kernel(
    const float* __restrict__ x, const unsigned short* __restrict__ fc1T,
    unsigned short* __restrict__ curq) {
  __shared__ __align__(16) float Af[128 * 32];
  __shared__ __align__(16) unsigned short Bs[128 * 32];

  const int tid = threadIdx.x;
  const int n0 = blockIdx.x * 128, m0 = blockIdx.y * 128;
  const int lane = tid & 63, wave = tid >> 6;
  const int wr = (wave >> 1) * 64, wc = (wave & 1) * 64;
  const int l16 = lane & 15, q = lane >> 4;

  const int a_irow = lane >> 3;
  const int a_g = (lane & 7) ^ (a_irow & 7);
  const int a_col = a_g * 4;
  const int b_irow = lane >> 2;
  const int b_col = (lane & 3) * 8;

  f32x4 acc[4][4];
  const f32x4 z4 = {0.f, 0.f, 0.f, 0.f};
#pragma unroll
  for (int i = 0; i < 4; ++i)
#pragma unroll
    for (int j = 0; j < 4; ++j) acc[i][j] = z4;

  for (int k0 = 0; k0 < KPAD; k0 += 32) {
#pragma unroll
    for (int l = 0; l < 4; ++l) {
      const int rbase = wave * 32 + l * 8;
      if (k0 + a_col < NIN)
        gl16(x + (size_t)(m0 + rbase + a_irow) * NIN + k0 + a_col,
             &Af[rbase * 32]);
    }
#pragma unroll
    for (int l = 0; l < 2; ++l) {
      const int rbase = wave * 32 + l * 16;
      gl16(fc1T + (size_t)(n0 + rbase + b_irow) * KPAD + k0 + b_col,
           &Bs[rbase * 32]);
    }
    __syncthreads();

    short8 av[4], bv[4];
#pragma unroll
    for (int i = 0; i < 4; ++i) {
      const int r = wr + i * 16 + l16;
      const int s0 = (2 * q) ^ (l16 & 7);
      const float4 alo = *(const float4*)&Af[r * 32 + s0 * 4];
      const float4 ahi = *(const float4*)&Af[r * 32 + (s0 ^ 1) * 4];
      union { short8 s; u32 u[4]; } p;
      p.u[0] = __builtin_amdgcn_perm(fu(alo.y), fu(alo.x), 0x07060302u);
      p.u[1] = __builtin_amdgcn_perm(fu(alo.w), fu(alo.z), 0x07060302u);
      p.u[2] = __builtin_amdgcn_perm(fu(ahi.y), fu(ahi.x), 0x07060302u);
      p.u[3] = __builtin_amdgcn_perm(fu(ahi.w), fu(ahi.z), 0x07060302u);
      av[i] = p.s;
      bv[i] = *(const short8*)&Bs[(wc + i * 16 + l16) * 32 + q * 8];
    }
#pragma unroll
    for (int i = 0; i < 4; ++i)
#pragma unroll
      for (int j = 0; j < 4; ++j)
        acc[i][j] = __builtin_amdgcn_mfma_f32_16x16x32_bf16(av[i], bv[j],
                                                            acc[i][j], 0, 0, 0);
    __syncthreads();
  }

#pragma unroll
  for (int i = 0; i < 4; ++i)
#pragma unroll
    for (int j = 0; j < 4; ++j) {
      const int row = m0 + wr + i * 16 + q * 4;
      const int col = n0 + wc + j * 16 + l16;
#pragma unroll
      for (int rr = 0; rr < 4; ++rr)
        curq[(size_t)(row + rr) * NH + col] = f2bf(acc[i][j][rr]);
    }
}

// ---- scan step block: 4 steps on CUR while (optionally) loading NXT --------
// All array indices compile-time -> everything stays in VGPRs (no scratch).
static __device__ __forceinline__ void scan4(
    const int tb, const size_t rowbase, const int h0, const unsigned lane,
    const unsigned short* __restrict__ curq, const float* __restrict__ wrec,
    const float* __restrict__ colsum, float* __restrict__ out,
    uint4 (&cur)[4][2], uint4 (&nxt)[4][2], const bool do_load,
    float (&mem)[16], float (&rs)[16],
    u32& spbits, u32& chgpack, u64& pend) {
  if (do_load) {
#pragma unroll
    for (int u = 0; u < 4; ++u) {
      const uint4* p = (const uint4*)&curq[(rowbase + tb + 4 + u) * NH + h0];
      nxt[u][0] = p[0];
      nxt[u][1] = p[1];
    }
  }
#pragma unroll
  for (int u = 0; u < 4; ++u) {
    const int t = tb + u;

    // ---- apply pending spike-set delta from step t-1 (wave-uniform) ----
    if (__builtin_expect(pend != 0ull, 0)) {
      if (__popcll(pend) >= 48) {
        // burst: reset from column sums, subtract currently-silent rows
#pragma unroll
        for (int c = 0; c < 16; c += 4) {
          const float4 cs = *(const float4*)&colsum[h0 + c];
          rs[c] = cs.x; rs[c + 1] = cs.y; rs[c + 2] = cs.z; rs[c + 3] = cs.w;
        }
        const u32 myz = (~spbits) & 0xFFFFu;
        u64 zm = __ballot(myz != 0);
        while (zm) {
          const int l = __builtin_ctzll(zm); zm &= zm - 1;
          u32 zb = __shfl(myz, l, 64);
          while (zb) {
            const int c = __builtin_ctz(zb); zb &= zb - 1;
            const float* w = &wrec[(size_t)(l * 16 + c) * NH + h0];
#pragma unroll
            for (int qq = 0; qq < 4; ++qq) {
              const float4 wv = *(const float4*)(w + 4 * qq);
              rs[4 * qq] -= wv.x; rs[4 * qq + 1] -= wv.y;
              rs[4 * qq + 2] -= wv.z; rs[4 * qq + 3] -= wv.w;
            }
          }
        }
      } else {
        u64 dm = pend;
        while (dm) {
          const int l = __builtin_ctzll(dm); dm &= dm - 1;
          const u32 pk = __shfl(chgpack, l, 64);
          u32 cbits = pk >> 16;
          while (cbits) {
            const int c = __builtin_ctz(cbits); cbits &= cbits - 1;
            const float s = ((pk >> c) & 1u) ? 1.0f : -1.0f;
            const float* w = &wrec[(size_t)(l * 16 + c) * NH + h0];
#pragma unroll
            for (int qq = 0; qq < 4; ++qq) {
              const float4 wv = *(const float4*)(w + 4 * qq);
              rs[4 * qq]     = fmaf(s, wv.x, rs[4 * qq]);
              rs[4 * qq + 1] = fmaf(s, wv.y, rs[4 * qq + 1]);
              rs[4 * qq + 2] = fmaf(s, wv.z, rs[4 * qq + 2]);
              rs[4 * qq + 3] = fmaf(s, wv.w, rs[4 * qq + 3]);
            }
          }
        }
      }
      pend = 0;
    }

    // ---- bf16 -> f32 extract ----
    const uint4 A = cur[u][0], B = cur[u][1];
    const u32 dw[8] = {A.x, A.y, A.z, A.w, B.x, B.y, B.z, B.w};
    float cin[16];
#pragma unroll
    for (int k = 0; k < 8; ++k) {
      cin[2 * k]     = uf(dw[k] << 16);
      cin[2 * k + 1] = uf(dw[k] & 0xFFFF0000u);
    }

    // ---- leaky integrate + fire (decay factor from spbits) ----
    u32 newbits = 0;
    float ns[16];
#pragma unroll
    for (int c = 0; c < 16; ++c) {
      const float f = ((spbits >> c) & 1u) ? 0.0f : DECAY;
      mem[c] = fmaf(mem[c], f, cin[c] + rs[c]);
      const bool fire = mem[c] >= 1.0f;
      ns[c] = fire ? 1.0f : 0.0f;
      newbits |= fire ? (1u << c) : 0u;
    }

    // ---- output slice spk[:, :102] ----
    if (lane < 7) {
      float2* o = (float2*)(out + (rowbase + t) * NSL + h0);
      const int n2 = (lane == 6) ? 3 : 8;
#pragma unroll
      for (int k = 0; k < 8; ++k)
        if (k < n2) o[k] = make_float2(ns[2 * k], ns[2 * k + 1]);
    }

    // ---- record deltas for step t+1 ----
    const u32 chg = spbits ^ newbits;
    pend = __ballot(chg != 0);
    chgpack = (chg << 16) | newbits;
    spbits = newbits;
  }
}

// ---- scan: one wave per batch; zero barriers; register double-buffer -------
__global__ __launch_bounds__(64) void scan_kernel(
    const unsigned short* __restrict__ curq, const float* __restrict__ wrec,
    const float* __restrict__ colsum, float* __restrict__ out) {
  const int b = blockIdx.x;
  const unsigned lane = threadIdx.x;
  const int h0 = (int)lane * 16;
  const size_t rowbase = (size_t)b * T_STEPS;

  float mem[16], rs[16];
#pragma unroll
  for (int c = 0; c < 16; ++c) { mem[c] = 0.f; rs[c] = 0.f; }
  u32 spbits = 0, chgpack = 0;
  u64 pend = 0;

  uint4 bufA[4][2], bufB[4][2];
#pragma unroll
  for (int u = 0; u < 4; ++u) {
    const uint4* p = (const uint4*)&curq[(rowbase + u) * NH + h0];
    bufA[u][0] = p[0];
    bufA[u][1] = p[1];
  }

#pragma unroll 1
  for (int tb = 0; tb + 8 <= T_STEPS; tb += 8) {
    scan4(tb,     rowbase, h0, lane, curq, wrec, colsum, out,
          bufA, bufB, true, mem, rs, spbits, chgpack, pend);
    scan4(tb + 4, rowbase, h0, lane, curq, wrec, colsum, out,
          bufB, bufA, true, mem, rs, spbits, chgpack, pend);
  }
  // tail: steps 496..499 from bufA, no further loads
  scan4(T_STEPS - 4, rowbase, h0, lane, curq, wrec, colsum, out,
        bufA, bufB, false, mem, rs, spbits, chgpack, pend);
}

extern "C" void kernel_launch(void* const* d_in, const int* in_sizes, int n_in,
                              void* d_out, int out_size, void* d_ws, size_t ws_size,
                              hipStream_t stream) {
  const float* x    = (const float*)d_in[0];  // [128][500][784] fp32
  const float* fc1  = (const float*)d_in[1];  // [784][1024] fp32
  const float* wrec = (const float*)d_in[2];  // [1024][1024] fp32
  float* out = (float*)d_out;                 // [128*500*102] + [1]

  unsigned short* fc1T = (unsigned short*)d_ws;                     // 1,638,400 B
  float* colsum = (float*)((char*)d_ws + 1638400);                  // 4,096 B
  unsigned short* curq = (unsigned short*)((char*)d_ws + 1642496);  // 131,072,000 B

  prep_kernel<<<dim3(25, 32), dim3(32, 8), 0, stream>>>(fc1, fc1T, colsum,
                                                        out + (out_size - 1));
  colsum_kernel<<<dim3(4, 32), 256, 0, stream>>>(wrec, colsum);
  gemm_kernel<<<dim3(8, 500), 256, 0, stream>>>(x, fc1T, curq);
  scan_kernel<<<dim3(NBATCH), 64, 0, stream>>>(curq, wrec, colsum, out);
}

// Round 5
// 632.178 us; speedup vs baseline: 1.4094x; 1.0595x over previous
//
#include <hip/hip_runtime.h>
#include <stdint.h>

#define T_STEPS 500
#define NBATCH  128
#define NIN     784
#define KPAD    832
#define NH      1024
#define NSL     102
#define DECAY   0.8807970779778823f

typedef __attribute__((ext_vector_type(8))) short short8;
typedef __attribute__((ext_vector_type(4))) float f32x4;
typedef unsigned int u32;
typedef unsigned long long u64;

static __device__ __forceinline__ unsigned short f2bf(float f) {
  union { float f; u32 u; } v; v.f = f;
  u32 r = (v.u + 0x7FFFu + ((v.u >> 16) & 1u)) >> 16;
  return (unsigned short)r;
}
static __device__ __forceinline__ float uf(u32 u) {
  union { u32 u; float f; } v; v.u = u; return v.f;
}
static __device__ __forceinline__ u32 fu(float f) {
  union { float f; u32 u; } v; v.f = f; return v.u;
}
static __device__ __forceinline__ void gl16(const void* g, void* l) {
  __builtin_amdgcn_global_load_lds((const __attribute__((address_space(1))) u32*)g,
                                   (__attribute__((address_space(3))) u32*)l, 16, 0, 0);
}

// ---- prep: transpose fc1 -> fc1T[1024][832] bf16 (K zero-padded) -----------
__global__ __launch_bounds__(256) void prep_kernel(
    const float* __restrict__ fc1, unsigned short* __restrict__ fc1T,
    float* __restrict__ out_last) {
  __shared__ float tile[32][33];
  const int bx = blockIdx.x;               // 26 k-blocks x 32 n-blocks
  const int kb = (bx % 26) * 32, nb = (bx / 26) * 32;
  const int tx = threadIdx.x & 31, ty = threadIdx.x >> 5;
#pragma unroll
  for (int i = 0; i < 4; ++i) {
    int k = kb + ty + i * 8, n = nb + tx;
    tile[ty + i * 8][tx] = (k < NIN) ? fc1[(size_t)k * NH + n] : 0.0f;
  }
  __syncthreads();
#pragma unroll
  for (int i = 0; i < 4; ++i) {
    int n = nb + ty + i * 8, k = kb + tx;
    fc1T[(size_t)n * KPAD + k] = f2bf(tile[tx][ty + i * 8]);
  }
  if (bx == 0 && threadIdx.x == 0) *out_last = 500.0f;
}

// ---- GEMM (BM=128, BN=256, BK=64) + embedded colsum (blockIdx.y==500) ------
// All LDS layouts XOR-swizzled via the gl16 GLOBAL address (lds slot is fixed
// at base+lane*16): A[128][64]f32 phys16B-chunk = g ^ (row&15);
// B[256][64]bf16 phys = g ^ (row&7). Both give 2-way-max bank aliasing (free).
__global__ __launch_bounds__(256, 2) void gemm_kernel(
    const float* __restrict__ x, const unsigned short* __restrict__ fc1T,
    const float* __restrict__ wrec, float* __restrict__ colsum,
    unsigned short* __restrict__ curq) {
  if (blockIdx.y == 500) {  // ---- colsum: 4 blocks, 256 cols each ----
    const int h = blockIdx.x * 256 + threadIdx.x;
    float s0 = 0.f, s1 = 0.f, s2 = 0.f, s3 = 0.f,
          s4 = 0.f, s5 = 0.f, s6 = 0.f, s7 = 0.f;
    for (int j = 0; j < NH; j += 8) {
      s0 += wrec[(size_t)(j + 0) * NH + h];
      s1 += wrec[(size_t)(j + 1) * NH + h];
      s2 += wrec[(size_t)(j + 2) * NH + h];
      s3 += wrec[(size_t)(j + 3) * NH + h];
      s4 += wrec[(size_t)(j + 4) * NH + h];
      s5 += wrec[(size_t)(j + 5) * NH + h];
      s6 += wrec[(size_t)(j + 6) * NH + h];
      s7 += wrec[(size_t)(j + 7) * NH + h];
    }
    colsum[h] = ((s0 + s1) + (s2 + s3)) + ((s4 + s5) + (s6 + s7));
    return;
  }

  __shared__ __align__(16) float Af[128 * 64];           // 32 KB
  __shared__ __align__(16) unsigned short Bs[256 * 64];  // 32 KB

  const int tid = threadIdx.x;
  const int n0 = blockIdx.x * 256, m0 = blockIdx.y * 128;
  const int lane = tid & 63, wave = tid >> 6;
  const int wr = (wave >> 1) * 64, wc = (wave & 1) * 128;
  const int l16 = lane & 15, q = lane >> 4;

  const int a_r = lane >> 4;    // row-in-call (4 rows / call)
  const int a_pc = lane & 15;   // phys 16B chunk (A: 16 chunks/row)
  const int b_r = lane >> 3;    // row-in-call (8 rows / call)
  const int b_pc = lane & 7;    // phys 16B chunk (B: 8 chunks/row)

  f32x4 acc[4][8];
  const f32x4 z4 = {0.f, 0.f, 0.f, 0.f};
#pragma unroll
  for (int i = 0; i < 4; ++i)
#pragma unroll
    for (int j = 0; j < 8; ++j) acc[i][j] = z4;

  for (int k0 = 0; k0 < KPAD; k0 += 64) {
#pragma unroll
    for (int l = 0; l < 8; ++l) {
      const int rbase = wave * 32 + l * 4;
      const int row = rbase + a_r;
      const int g = a_pc ^ (row & 15);  // global 16B chunk for my fixed slot
      if (k0 + g * 4 < NIN)             // pad chunks: stale LDS * B=0 -> 0
        gl16(x + (size_t)(m0 + row) * NIN + k0 + g * 4, &Af[rbase * 64]);
    }
#pragma unroll
    for (int l = 0; l < 8; ++l) {
      const int rbase = wave * 64 + l * 8;
      const int row = rbase + b_r;
      const int g = b_pc ^ (row & 7);
      gl16(fc1T + (size_t)(n0 + row) * KPAD + k0 + g * 8, &Bs[rbase * 64]);
    }
    __syncthreads();

#pragma unroll
    for (int h = 0; h < 2; ++h) {
      short8 av[4], bv[8];
#pragma unroll
      for (int i = 0; i < 4; ++i) {
        const int r = wr + i * 16 + l16;
        const int g0 = h * 8 + q * 2;
        const float4 alo = *(const float4*)&Af[r * 64 + ((g0)     ^ (r & 15)) * 4];
        const float4 ahi = *(const float4*)&Af[r * 64 + ((g0 + 1) ^ (r & 15)) * 4];
        union { short8 s; u32 u[4]; } p;
        p.u[0] = __builtin_amdgcn_perm(fu(alo.y), fu(alo.x), 0x07060302u);
        p.u[1] = __builtin_amdgcn_perm(fu(alo.w), fu(alo.z), 0x07060302u);
        p.u[2] = __builtin_amdgcn_perm(fu(ahi.y), fu(ahi.x), 0x07060302u);
        p.u[3] = __builtin_amdgcn_perm(fu(ahi.w), fu(ahi.z), 0x07060302u);
        av[i] = p.s;
      }
#pragma unroll
      for (int j = 0; j < 8; ++j) {
        const int r = wc + j * 16 + l16;
        const int c = h * 4 + q;
        bv[j] = *(const short8*)&Bs[r * 64 + ((c ^ (r & 7))) * 8];
      }
#pragma unroll
      for (int i = 0; i < 4; ++i)
#pragma unroll
        for (int j = 0; j < 8; ++j)
          acc[i][j] = __builtin_amdgcn_mfma_f32_16x16x32_bf16(av[i], bv[j],
                                                              acc[i][j], 0, 0, 0);
    }
    __syncthreads();
  }

  // C/D layout: col = lane&15, row = q*4 + reg
#pragma unroll
  for (int i = 0; i < 4; ++i)
#pragma unroll
    for (int j = 0; j < 8; ++j) {
      const int row = m0 + wr + i * 16 + q * 4;
      const int col = n0 + wc + j * 16 + l16;
#pragma unroll
      for (int rr = 0; rr < 4; ++rr)
        curq[(size_t)(row + rr) * NH + col] = f2bf(acc[i][j][rr]);
    }
}

// ---- scan step block: NP steps from cur, NL rows prefetched into nxt -------
template <int NP, int NL>
static __device__ __forceinline__ void scan_blk(
    const int tb, const size_t rowbase, const int h0, const unsigned lane,
    const unsigned short* __restrict__ curq, const float* __restrict__ wrec,
    const float* __restrict__ colsum, float* __restrict__ out,
    uint4 (&cur)[8][2], uint4 (&nxt)[8][2],
    float (&mem)[16], float (&rs)[16], float (&sp)[16],
    u32& spbits, u32& chgpack, u64& pend) {
#pragma unroll
  for (int u = 0; u < NL; ++u) {
    const uint4* p = (const uint4*)&curq[(rowbase + tb + 8 + u) * NH + h0];
    nxt[u][0] = p[0];
    nxt[u][1] = p[1];
  }
#pragma unroll
  for (int u = 0; u < NP; ++u) {
    const int t = tb + u;

    // ---- apply pending spike-set delta from step t-1 (wave-uniform) ----
    if (__builtin_expect(pend != 0ull, 0)) {
      if (__popcll(pend) >= 48) {  // burst: colsum minus silent rows
#pragma unroll
        for (int c = 0; c < 16; c += 4) {
          const float4 cs = *(const float4*)&colsum[h0 + c];
          rs[c] = cs.x; rs[c + 1] = cs.y; rs[c + 2] = cs.z; rs[c + 3] = cs.w;
        }
        const u32 myz = (~spbits) & 0xFFFFu;
        u64 zm = __ballot(myz != 0);
        while (zm) {
          const int l = __builtin_ctzll(zm); zm &= zm - 1;
          u32 zb = __shfl(myz, l, 64);
          while (zb) {
            const int c = __builtin_ctz(zb); zb &= zb - 1;
            const float* w = &wrec[(size_t)(l * 16 + c) * NH + h0];
#pragma unroll
            for (int qq = 0; qq < 4; ++qq) {
              const float4 wv = *(const float4*)(w + 4 * qq);
              rs[4 * qq] -= wv.x; rs[4 * qq + 1] -= wv.y;
              rs[4 * qq + 2] -= wv.z; rs[4 * qq + 3] -= wv.w;
            }
          }
        }
      } else {
        u64 dm = pend;
        while (dm) {
          const int l = __builtin_ctzll(dm); dm &= dm - 1;
          const u32 pk = __shfl(chgpack, l, 64);
          u32 cbits = pk >> 16;
          while (cbits) {
            const int c = __builtin_ctz(cbits); cbits &= cbits - 1;
            const float s = ((pk >> c) & 1u) ? 1.0f : -1.0f;
            const float* w = &wrec[(size_t)(l * 16 + c) * NH + h0];
#pragma unroll
            for (int qq = 0; qq < 4; ++qq) {
              const float4 wv = *(const float4*)(w + 4 * qq);
              rs[4 * qq]     = fmaf(s, wv.x, rs[4 * qq]);
              rs[4 * qq + 1] = fmaf(s, wv.y, rs[4 * qq + 1]);
              rs[4 * qq + 2] = fmaf(s, wv.z, rs[4 * qq + 2]);
              rs[4 * qq + 3] = fmaf(s, wv.w, rs[4 * qq + 3]);
            }
          }
        }
      }
      pend = 0;
    }

    // ---- bf16 -> f32 extract ----
    const uint4 Aa = cur[u][0], Bb = cur[u][1];
    const u32 dw[8] = {Aa.x, Aa.y, Aa.z, Aa.w, Bb.x, Bb.y, Bb.z, Bb.w};
    float cin[16];
#pragma unroll
    for (int k = 0; k < 8; ++k) {
      cin[2 * k]     = uf(dw[k] << 16);
      cin[2 * k + 1] = uf(dw[k] & 0xFFFF0000u);
    }

    // ---- leaky integrate + fire ----
    u32 newbits = 0;
    float ns[16];
#pragma unroll
    for (int c = 0; c < 16; ++c) {
      const float f = fmaf(-DECAY, sp[c], DECAY);  // DECAY*(1-sp)
      mem[c] = fmaf(mem[c], f, cin[c] + rs[c]);
      const bool fire = mem[c] >= 1.0f;
      ns[c] = fire ? 1.0f : 0.0f;
      newbits |= fire ? (1u << c) : 0u;
    }

    // ---- output slice spk[:, :102] ----
    if (lane < 7) {
      float2* o = (float2*)(out + (rowbase + t) * NSL + h0);
      const int n2 = (lane == 6) ? 3 : 8;
#pragma unroll
      for (int k = 0; k < 8; ++k)
        if (k < n2) o[k] = make_float2(ns[2 * k], ns[2 * k + 1]);
    }

    // ---- record deltas for step t+1 ----
    const u32 chg = spbits ^ newbits;
    pend = __ballot(chg != 0);
    chgpack = (chg << 16) | newbits;
    spbits = newbits;
#pragma unroll
    for (int c = 0; c < 16; ++c) sp[c] = ns[c];
  }
}

// ---- scan: one wave per batch; zero barriers; 8-step register pipeline -----
__global__ __launch_bounds__(64, 1) void scan_kernel(
    const unsigned short* __restrict__ curq, const float* __restrict__ wrec,
    const float* __restrict__ colsum, float* __restrict__ out) {
  const int b = blockIdx.x;
  const unsigned lane = threadIdx.x;
  const int h0 = (int)lane * 16;
  const size_t rowbase = (size_t)b * T_STEPS;

  float mem[16], rs[16], sp[16];
#pragma unroll
  for (int c = 0; c < 16; ++c) { mem[c] = 0.f; rs[c] = 0.f; sp[c] = 0.f; }
  u32 spbits = 0, chgpack = 0;
  u64 pend = 0;

  uint4 A[8][2], B[8][2];
#pragma unroll
  for (int u = 0; u < 8; ++u) {
    const uint4* p = (const uint4*)&curq[(rowbase + u) * NH + h0];
    A[u][0] = p[0];
    A[u][1] = p[1];
  }

  int tb = 0;
#pragma unroll 1
  for (int it = 0; it < 30; ++it) {  // steps 0..479
    scan_blk<8, 8>(tb, rowbase, h0, lane, curq, wrec, colsum, out,
                   A, B, mem, rs, sp, spbits, chgpack, pend);
    scan_blk<8, 8>(tb + 8, rowbase, h0, lane, curq, wrec, colsum, out,
                   B, A, mem, rs, sp, spbits, chgpack, pend);
    tb += 16;
  }
  scan_blk<8, 8>(480, rowbase, h0, lane, curq, wrec, colsum, out,
                 A, B, mem, rs, sp, spbits, chgpack, pend);  // loads 488..495
  scan_blk<8, 4>(488, rowbase, h0, lane, curq, wrec, colsum, out,
                 B, A, mem, rs, sp, spbits, chgpack, pend);  // loads 496..499
  scan_blk<4, 0>(496, rowbase, h0, lane, curq, wrec, colsum, out,
                 A, B, mem, rs, sp, spbits, chgpack, pend);  // tail
}

extern "C" void kernel_launch(void* const* d_in, const int* in_sizes, int n_in,
                              void* d_out, int out_size, void* d_ws, size_t ws_size,
                              hipStream_t stream) {
  const float* x    = (const float*)d_in[0];  // [128][500][784] fp32
  const float* fc1  = (const float*)d_in[1];  // [784][1024] fp32
  const float* wrec = (const float*)d_in[2];  // [1024][1024] fp32
  float* out = (float*)d_out;                 // [128*500*102] + [1]

  unsigned short* fc1T = (unsigned short*)d_ws;                     // 1,703,936 B
  float* colsum = (float*)((char*)d_ws + 1703936);                  // 4,096 B
  unsigned short* curq = (unsigned short*)((char*)d_ws + 1708032);  // 131,072,000 B

  prep_kernel<<<dim3(26 * 32), 256, 0, stream>>>(fc1, fc1T, out + (out_size - 1));
  gemm_kernel<<<dim3(4, 501), 256, 0, stream>>>(x, fc1T, wrec, colsum, curq);
  scan_kernel<<<dim3(NBATCH), 64, 0, stream>>>(curq, wrec, colsum, out);
}